// Round 11
// baseline (2190.861 us; speedup 1.0000x reference)
//
#include <hip/hip_runtime.h>

typedef __attribute__((ext_vector_type(8))) short short8;
typedef __attribute__((ext_vector_type(4))) float f32x4;

#define GLBP(p) ((const __attribute__((address_space(1))) void*)(p))
#define LDSP(p) ((__attribute__((address_space(3))) void*)(p))

__device__ __forceinline__ float bf2f(unsigned short u) {
  return __uint_as_float(((unsigned int)u) << 16);
}
__device__ __forceinline__ unsigned short f2bf(float f) {
  unsigned int u = __float_as_uint(f);
  u += 0x7fff + ((u >> 16) & 1);
  return (unsigned short)(u >> 16);
}

// global token -> (batch, pixel-y, pixel-x); windows are 14x14, 5x5 grid/batch
__device__ __forceinline__ void tok2pix(int gt, int& b, int& py, int& px) {
  int w = gt / 196, t = gt - w * 196;
  b = w / 25;
  int wr = w - b * 25;
  int wy = wr / 5, wx = wr - wy * 5;
  int ty = t / 14;
  py = wy * 14 + ty;
  px = wx * 14 + (t - ty * 14);
}

// ---------------- weight transpose fp32(K,N) -> bf16(N,K) ----------------
__global__ void k_transpose(const float* __restrict__ W, unsigned short* __restrict__ Wt,
                            int K, int N) {
  __shared__ float tile[32][33];
  int tx = threadIdx.x, ty = threadIdx.y;
  int n0 = blockIdx.x * 32, k0 = blockIdx.y * 32;
#pragma unroll
  for (int i = 0; i < 4; ++i)
    tile[ty + 8 * i][tx] = W[(size_t)(k0 + ty + 8 * i) * N + n0 + tx];
  __syncthreads();
#pragma unroll
  for (int i = 0; i < 4; ++i)
    Wt[(size_t)(n0 + ty + 8 * i) * K + k0 + tx] = f2bf(tile[tx][ty + 8 * i]);
}

// ---------------- LN1: one wave per token row; also seeds d_out image with x (residual) ----------------
__global__ __launch_bounds__(256) void k_ln1(const float* __restrict__ x,
                                             const float* __restrict__ g,
                                             const float* __restrict__ be,
                                             unsigned short* __restrict__ A1,
                                             float* __restrict__ outinit,
                                             int w0, int ctok) {
  int m = blockIdx.x * 4 + (threadIdx.x >> 6);
  int lane = threadIdx.x & 63;
  int b, py, px;
  tok2pix(w0 * 196 + m, b, py, px);
  bool valid = (m < ctok) && (py < 64) && (px < 64);
  size_t pixrow = ((size_t)((b * 64 + py) * 64 + px)) * 1280;
  const float* row = x + pixrow;
  float v[20];
#pragma unroll
  for (int i = 0; i < 20; ++i) v[i] = valid ? row[lane + 64 * i] : 0.f;
  float s = 0.f, ss = 0.f;
#pragma unroll
  for (int i = 0; i < 20; ++i) { s += v[i]; ss += v[i] * v[i]; }
#pragma unroll
  for (int o = 32; o > 0; o >>= 1) { s += __shfl_down(s, o); ss += __shfl_down(ss, o); }
  s = __shfl(s, 0);
  ss = __shfl(ss, 0);
  float mu = s * (1.f / 1280.f);
  float var = ss * (1.f / 1280.f) - mu * mu;
  float rinv = rsqrtf(var + 1e-6f);
  unsigned short* o1 = A1 + (size_t)m * 1280;
  float* oi = outinit + pixrow;
#pragma unroll
  for (int i = 0; i < 20; ++i) {
    int c = lane + 64 * i;
    o1[c] = f2bf((v[i] - mu) * rinv * g[c] + be[c]);
    if (valid) oi[c] = v[i];  // seed residual for gproj atomics (also resets each replay)
  }
}

// ---------------- LN2: one wave per row, input = fp32 attn-residual in d_out image ----------------
__global__ __launch_bounds__(256) void k_ln2(const float* __restrict__ AT,
                                             const float* __restrict__ g,
                                             const float* __restrict__ be,
                                             unsigned short* __restrict__ A2,
                                             int w0, int ctok) {
  int m = blockIdx.x * 4 + (threadIdx.x >> 6);
  int lane = threadIdx.x & 63;
  int b, py, px;
  tok2pix(w0 * 196 + m, b, py, px);
  bool valid = (m < ctok) && (py < 64) && (px < 64);
  const float* row = AT + ((size_t)((b * 64 + py) * 64 + px)) * 1280;
  float v[20];
#pragma unroll
  for (int i = 0; i < 20; ++i) v[i] = valid ? row[lane + 64 * i] : 0.f;
  float s = 0.f, ss = 0.f;
#pragma unroll
  for (int i = 0; i < 20; ++i) { s += v[i]; ss += v[i] * v[i]; }
#pragma unroll
  for (int o = 32; o > 0; o >>= 1) { s += __shfl_down(s, o); ss += __shfl_down(ss, o); }
  s = __shfl(s, 0);
  ss = __shfl(ss, 0);
  float mu = s * (1.f / 1280.f);
  float var = ss * (1.f / 1280.f) - mu * mu;
  float rinv = rsqrtf(var + 1e-6f);
  unsigned short* o1 = A2 + (size_t)m * 1280;
#pragma unroll
  for (int i = 0; i < 20; ++i) {
    int c = lane + 64 * i;
    o1[c] = f2bf((v[i] - mu) * rinv * g[c] + be[c]);
  }
}

// ---------------- unified 128x128 bf16 GEMM, BK=32, 3-slot ring (48KB -> 3 blocks/CU) ----------------
// C = A[M,Ktot] * Bt[N,Ktot]^T, split into SPLITK K-slices (separate blocks per slice).
// EPI 0: +bias -> head-major QKV bf16 [w][nh][qkv][196][80]     (SPLITK=1)
// EPI 2: +bias + exact gelu -> bf16 H                            (SPLITK=1)
// EPI 1/3: atomicAdd partial (+bias on slice 0) into fp32 d_out image (pre-seeded)
template <int EPI, int SPLITK>
__device__ __forceinline__ void gemm128_body(const unsigned short* __restrict__ A,
                                             const unsigned short* __restrict__ Bt,
                                             int Ktot, int N, int gx,
                                             const float* __restrict__ bias,
                                             void* __restrict__ outp,
                                             int w0, int ctok) {
  __shared__ __align__(16) char smem[49152];  // 3 slots x (A 8KB + B 8KB)
  int tid = threadIdx.x;
  int w = tid >> 6, lane = tid & 63;
  // bijective XCD swizzle (m204) over the full grid, then decode (slice, tile)
  int nwg = gridDim.x, bid = blockIdx.x;
  int q = nwg >> 3, r = nwg & 7;
  int xcd = bid & 7, loc = bid >> 3;
  int wg = (xcd < r ? xcd * (q + 1) : r * (q + 1) + (xcd - r) * q) + loc;
  int ntiles = nwg / SPLITK;
  int kslice = wg / ntiles, tile = wg - kslice * ntiles;
  int bx = tile % gx, by = tile / gx;
  int mBase = by * 128, nBase = bx * 128;
  int K = Ktot / SPLITK;
  int k0elem = kslice * K;
  int wr = w >> 1, wc = w & 1;
  int la = lane & 15, lg = lane >> 4;

  int srow = tid >> 2;  // 0..63
  int schunk = (tid & 3) ^ ((srow >> 1) & 3);  // pre-swizzled source chunk
  const char* pa[2];
  const char* pb[2];
#pragma unroll
  for (int i = 0; i < 2; ++i) {
    pa[i] = (const char*)A + ((size_t)(mBase + srow + i * 64) * Ktot + k0elem) * 2 + (schunk << 4);
    pb[i] = (const char*)Bt + ((size_t)(nBase + srow + i * 64) * Ktot + k0elem) * 2 + (schunk << 4);
  }
  int ldst = tid * 16;

  auto STAGE = [&](int slot, size_t ko) {
    int b = slot * 16384;
#pragma unroll
    for (int i = 0; i < 2; ++i)
      __builtin_amdgcn_global_load_lds(GLBP(pa[i] + ko), LDSP(smem + b + i * 4096 + ldst), 16, 0, 0);
#pragma unroll
    for (int i = 0; i < 2; ++i)
      __builtin_amdgcn_global_load_lds(GLBP(pb[i] + ko), LDSP(smem + b + 8192 + i * 4096 + ldst), 16, 0, 0);
  };

  int offA[4], offB[4];
#pragma unroll
  for (int m = 0; m < 4; ++m) {
    int rr = wr * 64 + m * 16 + la;
    offA[m] = rr * 64 + ((lg ^ ((rr >> 1) & 3)) << 4);
  }
#pragma unroll
  for (int n = 0; n < 4; ++n) {
    int rr = wc * 64 + n * 16 + la;
    offB[n] = 8192 + rr * 64 + ((lg ^ ((rr >> 1) & 3)) << 4);
  }

  const f32x4 z4 = {0.f, 0.f, 0.f, 0.f};
  f32x4 acc[4][4];
#pragma unroll
  for (int m = 0; m < 4; ++m)
#pragma unroll
    for (int n = 0; n < 4; ++n) acc[m][n] = z4;

  int NT = K >> 5;
  STAGE(0, 0);
  STAGE(1, 64);
  int rs = 0;
  for (int t = 0; t < NT; ++t) {
    if (t + 1 < NT)
      asm volatile("s_waitcnt vmcnt(4)" ::: "memory");
    else
      asm volatile("s_waitcnt vmcnt(0)" ::: "memory");
    __builtin_amdgcn_s_barrier();
    __builtin_amdgcn_sched_barrier(0);
    if (t + 2 < NT) {
      int ws = rs + 2;
      if (ws >= 3) ws -= 3;
      STAGE(ws, (size_t)(t + 2) * 64);
    }
    const char* buf = (const char*)smem + rs * 16384;
    short8 af[4], bfr[4];
#pragma unroll
    for (int n = 0; n < 4; ++n) bfr[n] = *(const short8*)(buf + offB[n]);
#pragma unroll
    for (int m = 0; m < 4; ++m) af[m] = *(const short8*)(buf + offA[m]);
    __builtin_amdgcn_s_setprio(1);
#pragma unroll
    for (int m = 0; m < 4; ++m)
#pragma unroll
      for (int n = 0; n < 4; ++n)
        acc[m][n] = __builtin_amdgcn_mfma_f32_16x16x32_bf16(af[m], bfr[n], acc[m][n], 0, 0, 0);
    __builtin_amdgcn_s_setprio(0);
    rs = (rs == 2) ? 0 : rs + 1;
  }

#pragma unroll
  for (int m = 0; m < 4; ++m) {
#pragma unroll
    for (int n = 0; n < 4; ++n) {
      int col = nBase + wc * 64 + n * 16 + la;
      float bcol = (SPLITK == 1 || kslice == 0) ? bias[col] : 0.f;
#pragma unroll
      for (int j = 0; j < 4; ++j) {
        int row = mBase + wr * 64 + m * 16 + lg * 4 + j;
        float v = acc[m][n][j] + bcol;
        if (EPI == 0) {
          if (row < ctok) {
            int wloc = row / 196, tt = row - wloc * 196;
            int which = col / 1280, cr = col - which * 1280;
            int nh = cr / 80, d = cr - nh * 80;
            ((unsigned short*)outp)[((((size_t)wloc * 16 + nh) * 3 + which) * 196 + tt) * 80 + d] =
                f2bf(v);
          }
        } else if (EPI == 2) {
          float gg = 0.5f * v * (1.f + erff(v * 0.70710678118654752f));
          ((unsigned short*)outp)[(size_t)row * N + col] = f2bf(gg);
        } else {
          if (row < ctok) {
            int b, py, px;
            tok2pix(w0 * 196 + row, b, py, px);
            if (py < 64 && px < 64)
              atomicAdd((float*)outp + ((size_t)((b * 64 + py) * 64 + px)) * 1280 + col, v);
          }
        }
      }
    }
  }
}

__global__ __launch_bounds__(256, 3) void k_gqkv(const unsigned short* A, const unsigned short* Bt,
                                                 int K, int N, int gx, const float* bias, void* o,
                                                 int w0, int ct) {
  gemm128_body<0, 1>(A, Bt, K, N, gx, bias, o, w0, ct);
}
__global__ __launch_bounds__(256, 3) void k_gproj(const unsigned short* A, const unsigned short* Bt,
                                                  int K, int N, int gx, const float* bias, void* o,
                                                  int w0, int ct) {
  gemm128_body<1, 2>(A, Bt, K, N, gx, bias, o, w0, ct);
}
__global__ __launch_bounds__(256, 3) void k_gmlp1(const unsigned short* A, const unsigned short* Bt,
                                                  int K, int N, int gx, const float* bias, void* o,
                                                  int w0, int ct) {
  gemm128_body<2, 1>(A, Bt, K, N, gx, bias, o, w0, ct);
}
__global__ __launch_bounds__(256, 3) void k_gmlp2(const unsigned short* A, const unsigned short* Bt,
                                                  int K, int N, int gx, const float* bias, void* o,
                                                  int w0, int ct) {
  gemm128_body<3, 4>(A, Bt, K, N, gx, bias, o, w0, ct);
}

// ---------------- attention: one block (512 thr) per (window, head), head-major QKV ----------------
__global__ __launch_bounds__(512, 1) void k_attn(const unsigned short* __restrict__ qkv,
                                                 const float* __restrict__ rph,
                                                 const float* __restrict__ rpw,
                                                 unsigned short* __restrict__ AO) {
  __shared__ unsigned short Ks[208 * 104];   // [key][d] stride 52dw (2-way free)
  __shared__ unsigned short Vt[80 * 232];    // [d][key] stride 116dw (2-way free)
  __shared__ unsigned short Ps[8][16 * 232];
  __shared__ unsigned short Bls[196 * 28];   // [t][0..13]=bh(ky), [14..27]=bw(kx)
  int wh = blockIdx.x;
  int w = wh >> 4, nh = wh & 15;
  int tid = threadIdx.x, wid = tid >> 6, lane = tid & 63;
  int la = lane & 15, lg = lane >> 4;
  const unsigned short* qb = qkv + (size_t)wh * 47040;
  const unsigned short* kb = qb + 15680;
  const unsigned short* vb = qb + 31360;
  const short8 z8 = {0, 0, 0, 0, 0, 0, 0, 0};

  for (int c = tid; c < 208 * 13; c += 512) {
    int t = c / 13, seg = c - t * 13;
    short8 kv = z8;
    if (t < 196 && seg < 10) kv = *(const short8*)(kb + (size_t)t * 80 + seg * 8);
    *(short8*)(Ks + t * 104 + seg * 8) = kv;
  }
  for (int c = tid; c < 1960; c += 512) {
    int t = c / 10, d8 = (c - t * 10) * 8;
    short8 vv = *(const short8*)(vb + (size_t)t * 80 + d8);
#pragma unroll
    for (int e = 0; e < 8; ++e) Vt[(d8 + e) * 232 + t] = (unsigned short)vv[e];
  }
  for (int i = tid; i < 80 * 36; i += 512) Vt[(i / 36) * 232 + 196 + (i % 36)] = 0;
  for (int id = tid; id < 196 * 28; id += 512) {
    int t = id / 28, c = id - t * 28;
    int y = t / 14, xx = t - y * 14;
    const float* R = (c < 14) ? (rph + (size_t)(y - c + 13) * 80)
                              : (rpw + (size_t)(xx - (c - 14) + 13) * 80);
    const unsigned short* qq = qb + (size_t)t * 80;
    float acc = 0.f;
#pragma unroll
    for (int d8 = 0; d8 < 10; ++d8) {
      short8 qv = *(const short8*)(qq + d8 * 8);
      const float4* Rv = (const float4*)(R + d8 * 8);
      float4 ra = Rv[0], rb = Rv[1];
      acc += bf2f((unsigned short)qv[0]) * ra.x + bf2f((unsigned short)qv[1]) * ra.y +
             bf2f((unsigned short)qv[2]) * ra.z + bf2f((unsigned short)qv[3]) * ra.w +
             bf2f((unsigned short)qv[4]) * rb.x + bf2f((unsigned short)qv[5]) * rb.y +
             bf2f((unsigned short)qv[6]) * rb.z + bf2f((unsigned short)qv[7]) * rb.w;
    }
    Bls[id] = f2bf(acc);
  }
  __syncthreads();

  int kyv[13], kxv[13];
#pragma unroll
  for (int ci = 0; ci < 13; ++ci) {
    int key = ci * 16 + la;
    kyv[ci] = key / 14;
    kxv[ci] = key - kyv[ci] * 14;
  }

  const float scale = 0.111803398874989485f;  // 80^-0.5
  const f32x4 z4 = {0.f, 0.f, 0.f, 0.f};
  unsigned short* P = Ps[wid];

  auto process = [&](int rb) {
    short8 qa[3];
    int tq = rb * 16 + la;
    if (tq >= 196) tq = 0;
#pragma unroll
    for (int kk = 0; kk < 3; ++kk) {
      int d = kk * 32 + lg * 8;
      qa[kk] = (kk < 2 || lg < 2) ? *(const short8*)(qb + (size_t)tq * 80 + d) : z8;
    }
    f32x4 s[13];
#pragma unroll
    for (int i = 0; i < 13; ++i) s[i] = z4;
#pragma unroll
    for (int kk = 0; kk < 3; ++kk) {
#pragma unroll
      for (int ni = 0; ni < 13; ++ni) {
        short8 bb = *(const short8*)(Ks + (ni * 16 + la) * 104 + kk * 32 + lg * 8);
        s[ni] = __builtin_amdgcn_mfma_f32_16x16x32_bf16(qa[kk], bb, s[ni], 0, 0, 0);
      }
    }
#pragma unroll
    for (int j = 0; j < 4; ++j) {
      int rloc = lg * 4 + j;
      int t = rb * 16 + rloc;
      bool tval = t < 196;
      const unsigned short* Bp = Bls + (tval ? t : 0) * 28;
      float v[13];
      float mx = -3e30f;
#pragma unroll
      for (int ci = 0; ci < 13; ++ci) {
        int key = ci * 16 + la;
        float val = s[ci][j] * scale;
        if (key < 196 && tval) val += bf2f(Bp[kyv[ci]]) + bf2f(Bp[14 + kxv[ci]]);
        if (key >= 196 || !tval) val = -3e30f;
        v[ci] = val;
        mx = fmaxf(mx, val);
      }
#pragma unroll
      for (int o = 1; o < 16; o <<= 1) mx = fmaxf(mx, __shfl_xor(mx, o));
      float sum = 0.f;
#pragma unroll
      for (int ci = 0; ci < 13; ++ci) {
        float e = __expf(v[ci] - mx);
        v[ci] = e;
        sum += e;
      }
#pragma unroll
      for (int o = 1; o < 16; o <<= 1) sum += __shfl_xor(sum, o);
      float inv = 1.f / sum;
#pragma unroll
      for (int ci = 0; ci < 13; ++ci) P[rloc * 232 + ci * 16 + la] = f2bf(v[ci] * inv);
      P[rloc * 232 + 208 + la] = 0;
    }
    f32x4 o5[5];
#pragma unroll
    for (int i = 0; i < 5; ++i) o5[i] = z4;
#pragma unroll
    for (int kc = 0; kc < 7; ++kc) {
      short8 aa = *(const short8*)(P + la * 232 + kc * 32 + lg * 8);
#pragma unroll
      for (int ni = 0; ni < 5; ++ni) {
        short8 bb = *(const short8*)(Vt + (ni * 16 + la) * 232 + kc * 32 + lg * 8);
        o5[ni] = __builtin_amdgcn_mfma_f32_16x16x32_bf16(aa, bb, o5[ni], 0, 0, 0);
      }
    }
#pragma unroll
    for (int ni = 0; ni < 5; ++ni)
#pragma unroll
      for (int j = 0; j < 4; ++j) {
        int t = rb * 16 + lg * 4 + j;
        if (t < 196)
          AO[((size_t)w * 196 + t) * 1280 + nh * 80 + ni * 16 + la] = f2bf(o5[ni][j]);
      }
  };

  process(wid);                   // rb 0..7
  if (wid < 5) process(wid + 8);  // rb 8..12
}

extern "C" void kernel_launch(void* const* d_in, const int* in_sizes, int n_in,
                              void* d_out, int out_size, void* d_ws, size_t ws_size,
                              hipStream_t stream) {
  const float* x = (const float*)d_in[0];
  const float* ln1g = (const float*)d_in[1];
  const float* ln1b = (const float*)d_in[2];
  const float* qkvw = (const float*)d_in[3];
  const float* qkvb = (const float*)d_in[4];
  const float* projw = (const float*)d_in[5];
  const float* projb = (const float*)d_in[6];
  const float* rph = (const float*)d_in[7];
  const float* rpw = (const float*)d_in[8];
  const float* ln2g = (const float*)d_in[9];
  const float* ln2b = (const float*)d_in[10];
  const float* w1 = (const float*)d_in[11];
  const float* b1 = (const float*)d_in[12];
  const float* w2 = (const float*)d_in[13];
  const float* b2 = (const float*)d_in[14];
  float* out = (float*)d_out;

  const size_t woff = (3840ull * 1280 + 1280ull * 1280 + 5120ull * 1280 + 1280ull * 5120) * 2;
  // per-chunk ws: A1/A2(2560B/row) + QKV(7680B/row) + AO(2560B/row); H(10240) overlays QKV+AO.
  const int NWopts[12] = {25, 20, 18, 16, 14, 12, 10, 8, 5, 4, 2, 1};
  int NW = 0, Mb = 0;
  for (int i = 0; i < 12; ++i) {
    int nw = NWopts[i];
    int mb = ((nw * 196 + 255) / 256) * 256;
    size_t tot = woff + (size_t)mb * 12800;
    if (tot <= ws_size) { NW = nw; Mb = mb; break; }
  }
  if (!NW) return;

  char* p = (char*)d_ws;
  unsigned short* qkvwT = (unsigned short*)p; p += 3840ull * 1280 * 2;
  unsigned short* projwT = (unsigned short*)p; p += 1280ull * 1280 * 2;
  unsigned short* w1T = (unsigned short*)p; p += 5120ull * 1280 * 2;
  unsigned short* w2T = (unsigned short*)p; p += 1280ull * 5120 * 2;
  unsigned short* A1 = (unsigned short*)p; p += (size_t)Mb * 2560;
  unsigned short* QKV = (unsigned short*)p; p += (size_t)Mb * 7680;
  unsigned short* AO = (unsigned short*)p;
  unsigned short* Hb = QKV;  // MLP hidden (Mb x 5120) overlays QKV+AO (contiguous, both dead)
  unsigned short* A2 = A1;   // LN2 out overlays LN1 out

  k_transpose<<<dim3(120, 40), dim3(32, 8), 0, stream>>>(qkvw, qkvwT, 1280, 3840);
  k_transpose<<<dim3(40, 40), dim3(32, 8), 0, stream>>>(projw, projwT, 1280, 1280);
  k_transpose<<<dim3(160, 40), dim3(32, 8), 0, stream>>>(w1, w1T, 1280, 5120);
  k_transpose<<<dim3(40, 160), dim3(32, 8), 0, stream>>>(w2, w2T, 5120, 1280);

  int gy = Mb / 128;
  int nchunks = (100 + NW - 1) / NW;
  for (int c = 0; c < nchunks; ++c) {
    int w0 = c * NW;
    int cw = (100 - w0 < NW) ? (100 - w0) : NW;
    int ctok = cw * 196;
    k_ln1<<<Mb / 4, 256, 0, stream>>>(x, ln1g, ln1b, A1, out, w0, ctok);
    k_gqkv<<<30 * gy, 256, 0, stream>>>(A1, qkvwT, 1280, 3840, 30, qkvb, (void*)QKV, w0, ctok);
    k_attn<<<cw * 16, 512, 0, stream>>>(QKV, rph, rpw, AO);
    k_gproj<<<2 * 10 * gy, 256, 0, stream>>>(AO, projwT, 1280, 1280, 10, projb, (void*)out, w0, ctok);
    k_ln2<<<Mb / 4, 256, 0, stream>>>(out, ln2g, ln2b, A2, w0, ctok);
    k_gmlp1<<<40 * gy, 256, 0, stream>>>(A2, w1T, 1280, 5120, 40, b1, (void*)Hb, w0, ctok);
    k_gmlp2<<<4 * 10 * gy, 256, 0, stream>>>(Hb, w2T, 5120, 1280, 10, b2, (void*)out, w0, ctok);
  }
}

// Round 12
// 1817.435 us; speedup vs baseline: 1.2055x; 1.2055x over previous
//
#include <hip/hip_runtime.h>

typedef __attribute__((ext_vector_type(8))) short short8;
typedef __attribute__((ext_vector_type(4))) float f32x4;

#define GLBP(p) ((const __attribute__((address_space(1))) void*)(p))
#define LDSP(p) ((__attribute__((address_space(3))) void*)(p))

__device__ __forceinline__ float bf2f(unsigned short u) {
  return __uint_as_float(((unsigned int)u) << 16);
}
__device__ __forceinline__ unsigned short f2bf(float f) {
  unsigned int u = __float_as_uint(f);
  u += 0x7fff + ((u >> 16) & 1);
  return (unsigned short)(u >> 16);
}

// global token -> (batch, pixel-y, pixel-x); windows are 14x14, 5x5 grid/batch
__device__ __forceinline__ void tok2pix(int gt, int& b, int& py, int& px) {
  int w = gt / 196, t = gt - w * 196;
  b = w / 25;
  int wr = w - b * 25;
  int wy = wr / 5, wx = wr - wy * 5;
  int ty = t / 14;
  py = wy * 14 + ty;
  px = wx * 14 + (t - ty * 14);
}

// ---------------- weight transpose fp32(K,N) -> bf16(N,K) ----------------
__global__ void k_transpose(const float* __restrict__ W, unsigned short* __restrict__ Wt,
                            int K, int N) {
  __shared__ float tile[32][33];
  int tx = threadIdx.x, ty = threadIdx.y;
  int n0 = blockIdx.x * 32, k0 = blockIdx.y * 32;
#pragma unroll
  for (int i = 0; i < 4; ++i)
    tile[ty + 8 * i][tx] = W[(size_t)(k0 + ty + 8 * i) * N + n0 + tx];
  __syncthreads();
#pragma unroll
  for (int i = 0; i < 4; ++i)
    Wt[(size_t)(n0 + ty + 8 * i) * K + k0 + tx] = f2bf(tile[tx][ty + 8 * i]);
}

// ---------------- LN1: one wave per token row ----------------
__global__ __launch_bounds__(256) void k_ln1(const float* __restrict__ x,
                                             const float* __restrict__ g,
                                             const float* __restrict__ be,
                                             unsigned short* __restrict__ A1,
                                             int w0, int ctok) {
  int m = blockIdx.x * 4 + (threadIdx.x >> 6);
  int lane = threadIdx.x & 63;
  int b, py, px;
  tok2pix(w0 * 196 + m, b, py, px);
  bool valid = (m < ctok) && (py < 64) && (px < 64);
  const float* row = x + ((size_t)((b * 64 + py) * 64 + px)) * 1280;
  float v[20];
#pragma unroll
  for (int i = 0; i < 20; ++i) v[i] = valid ? row[lane + 64 * i] : 0.f;
  float s = 0.f, ss = 0.f;
#pragma unroll
  for (int i = 0; i < 20; ++i) { s += v[i]; ss += v[i] * v[i]; }
#pragma unroll
  for (int o = 32; o > 0; o >>= 1) { s += __shfl_down(s, o); ss += __shfl_down(ss, o); }
  s = __shfl(s, 0);
  ss = __shfl(ss, 0);
  float mu = s * (1.f / 1280.f);
  float var = ss * (1.f / 1280.f) - mu * mu;
  float rinv = rsqrtf(var + 1e-6f);
  unsigned short* o1 = A1 + (size_t)m * 1280;
#pragma unroll
  for (int i = 0; i < 20; ++i) {
    int c = lane + 64 * i;
    o1[c] = f2bf((v[i] - mu) * rinv * g[c] + be[c]);
  }
}

// ---------------- LN2: one wave per bf16 ATTN row ----------------
__global__ __launch_bounds__(256) void k_ln2(const unsigned short* __restrict__ AT,
                                             const float* __restrict__ g,
                                             const float* __restrict__ be,
                                             unsigned short* __restrict__ A2) {
  int m = blockIdx.x * 4 + (threadIdx.x >> 6);
  int lane = threadIdx.x & 63;
  const unsigned short* row = AT + (size_t)m * 1280;
  float v[20];
#pragma unroll
  for (int i = 0; i < 20; ++i) v[i] = bf2f(row[lane + 64 * i]);
  float s = 0.f, ss = 0.f;
#pragma unroll
  for (int i = 0; i < 20; ++i) { s += v[i]; ss += v[i] * v[i]; }
#pragma unroll
  for (int o = 32; o > 0; o >>= 1) { s += __shfl_down(s, o); ss += __shfl_down(ss, o); }
  s = __shfl(s, 0);
  ss = __shfl(ss, 0);
  float mu = s * (1.f / 1280.f);
  float var = ss * (1.f / 1280.f) - mu * mu;
  float rinv = rsqrtf(var + 1e-6f);
  unsigned short* o1 = A2 + (size_t)m * 1280;
#pragma unroll
  for (int i = 0; i < 20; ++i) {
    int c = lane + 64 * i;
    o1[c] = f2bf((v[i] - mu) * rinv * g[c] + be[c]);
  }
}

// ---------------- 256x128 bf16 GEMM, BK=32, 3-slot ring (72KB -> 2 blocks/CU) ----------------
// EPI 0: +bias -> head-major QKV bf16 [w][nh][q|k|v][196][80]   EPI 2: +bias+gelu -> bf16
template <int EPI>
__device__ __forceinline__ void gemm_body(const unsigned short* __restrict__ A,
                                          const unsigned short* __restrict__ Bt,
                                          int K, int N, int gx,
                                          const float* __restrict__ bias,
                                          void* __restrict__ outp, int ctok) {
  __shared__ __align__(16) char smem[73728];  // 3 slots x (A 16KB + B 8KB)
  int tid = threadIdx.x;
  int w = tid >> 6, lane = tid & 63;
  int nwg = gridDim.x, bid = blockIdx.x;
  int q = nwg >> 3, r = nwg & 7;
  int xcd = bid & 7, loc = bid >> 3;
  int wg = (xcd < r ? xcd * (q + 1) : r * (q + 1) + (xcd - r) * q) + loc;
  int bx = wg % gx, by = wg / gx;
  int mBase = by * 256, nBase = bx * 128;
  int wr = w >> 2, wc = w & 3;
  int la = lane & 15, lg = lane >> 4;

  int srow = tid >> 2;
  int schunk = (tid & 3) ^ ((srow >> 1) & 3);
  const char* pa0 = (const char*)A + (size_t)(mBase + srow) * K * 2 + (schunk << 4);
  const char* pa1 = (const char*)A + (size_t)(mBase + 128 + srow) * K * 2 + (schunk << 4);
  const char* pb0 = (const char*)Bt + (size_t)(nBase + srow) * K * 2 + (schunk << 4);
  int ldst = tid * 16;

  auto STAGE = [&](int slot, size_t ko) {
    int b = slot * 24576;
    __builtin_amdgcn_global_load_lds(GLBP(pa0 + ko), LDSP(smem + b + ldst), 16, 0, 0);
    __builtin_amdgcn_global_load_lds(GLBP(pa1 + ko), LDSP(smem + b + 8192 + ldst), 16, 0, 0);
    __builtin_amdgcn_global_load_lds(GLBP(pb0 + ko), LDSP(smem + b + 16384 + ldst), 16, 0, 0);
  };

  int offA[8], offB[2];
#pragma unroll
  for (int m = 0; m < 8; ++m) {
    int rr = wr * 128 + m * 16 + la;
    offA[m] = rr * 64 + ((lg ^ ((rr >> 1) & 3)) << 4);
  }
#pragma unroll
  for (int n = 0; n < 2; ++n) {
    int rr = wc * 32 + n * 16 + la;
    offB[n] = 16384 + rr * 64 + ((lg ^ ((rr >> 1) & 3)) << 4);
  }

  const f32x4 z4 = {0.f, 0.f, 0.f, 0.f};
  f32x4 acc[8][2];
#pragma unroll
  for (int m = 0; m < 8; ++m)
#pragma unroll
    for (int n = 0; n < 2; ++n) acc[m][n] = z4;

  int NT = K >> 5;
  STAGE(0, 0);
  STAGE(1, 64);
  int rs = 0;
  for (int t = 0; t < NT; ++t) {
    if (t + 1 < NT)
      asm volatile("s_waitcnt vmcnt(3)" ::: "memory");
    else
      asm volatile("s_waitcnt vmcnt(0)" ::: "memory");
    __builtin_amdgcn_s_barrier();
    __builtin_amdgcn_sched_barrier(0);
    if (t + 2 < NT) {
      int ws = rs + 2;
      if (ws >= 3) ws -= 3;
      STAGE(ws, (size_t)(t + 2) * 64);
    }
    const char* buf = (const char*)smem + rs * 24576;
    short8 af[4], bfr[2];
#pragma unroll
    for (int n = 0; n < 2; ++n) bfr[n] = *(const short8*)(buf + offB[n]);
#pragma unroll
    for (int m = 0; m < 4; ++m) af[m] = *(const short8*)(buf + offA[m]);
    __builtin_amdgcn_s_setprio(1);
#pragma unroll
    for (int m = 0; m < 4; ++m)
#pragma unroll
      for (int n = 0; n < 2; ++n)
        acc[m][n] = __builtin_amdgcn_mfma_f32_16x16x32_bf16(af[m], bfr[n], acc[m][n], 0, 0, 0);
    __builtin_amdgcn_s_setprio(0);
    __builtin_amdgcn_sched_barrier(0);
#pragma unroll
    for (int m = 0; m < 4; ++m) af[m] = *(const short8*)(buf + offA[m + 4]);
    __builtin_amdgcn_s_setprio(1);
#pragma unroll
    for (int m = 0; m < 4; ++m)
#pragma unroll
      for (int n = 0; n < 2; ++n)
        acc[m + 4][n] = __builtin_amdgcn_mfma_f32_16x16x32_bf16(af[m], bfr[n], acc[m + 4][n], 0, 0, 0);
    __builtin_amdgcn_s_setprio(0);
    rs = (rs == 2) ? 0 : rs + 1;
  }

#pragma unroll
  for (int m = 0; m < 8; ++m) {
#pragma unroll
    for (int n = 0; n < 2; ++n) {
      int col = nBase + wc * 32 + n * 16 + la;
      float bcol = bias[col];
#pragma unroll
      for (int j = 0; j < 4; ++j) {
        int row = mBase + wr * 128 + m * 16 + lg * 4 + j;
        float v = acc[m][n][j] + bcol;
        if (EPI == 0) {
          if (row < ctok) {
            int wloc = row / 196, tt = row - wloc * 196;
            int which = col / 1280, cr = col - which * 1280;
            int nh = cr / 80, d = cr - nh * 80;
            ((unsigned short*)outp)[((((size_t)wloc * 16 + nh) * 3 + which) * 196 + tt) * 80 + d] =
                f2bf(v);
          }
        } else {
          float gg = 0.5f * v * (1.f + erff(v * 0.70710678118654752f));
          ((unsigned short*)outp)[(size_t)row * N + col] = f2bf(gg);
        }
      }
    }
  }
}

__global__ __launch_bounds__(512, 2) void k_gqkv(const unsigned short* A, const unsigned short* Bt,
                                                 int K, int N, int gx, const float* bias, void* o,
                                                 int ct) {
  gemm_body<0>(A, Bt, K, N, gx, bias, o, ct);
}
__global__ __launch_bounds__(512, 2) void k_gmlp1(const unsigned short* A, const unsigned short* Bt,
                                                  int K, int N, int gx, const float* bias, void* o,
                                                  int ct) {
  gemm_body<2>(A, Bt, K, N, gx, bias, o, ct);
}

// ---------------- 128x128 bf16 GEMM, BK=32, 3-slot ring (48KB -> 3 blocks/CU) ----------------
// EPI 1: +bias + window-residual(x fp32 image) -> bf16 ATTN rows
// EPI 3: +bias + ATTN(bf16) residual -> fp32 d_out image (write-once)
template <int EPI>
__device__ __forceinline__ void gemm128_body(const unsigned short* __restrict__ A,
                                             const unsigned short* __restrict__ Bt,
                                             int K, int N, int gx,
                                             const float* __restrict__ bias,
                                             void* __restrict__ outp,
                                             const void* __restrict__ res,
                                             int w0, int ctok) {
  __shared__ __align__(16) char smem[49152];  // 3 slots x (A 8KB + B 8KB)
  int tid = threadIdx.x;
  int w = tid >> 6, lane = tid & 63;
  int nwg = gridDim.x, bid = blockIdx.x;
  int q = nwg >> 3, r = nwg & 7;
  int xcd = bid & 7, loc = bid >> 3;
  int wg = (xcd < r ? xcd * (q + 1) : r * (q + 1) + (xcd - r) * q) + loc;
  int bx = wg % gx, by = wg / gx;
  int mBase = by * 128, nBase = bx * 128;
  int wr = w >> 1, wc = w & 1;
  int la = lane & 15, lg = lane >> 4;

  int srow = tid >> 2;  // 0..63
  int schunk = (tid & 3) ^ ((srow >> 1) & 3);
  const char* pa[2];
  const char* pb[2];
#pragma unroll
  for (int i = 0; i < 2; ++i) {
    pa[i] = (const char*)A + (size_t)(mBase + srow + i * 64) * K * 2 + (schunk << 4);
    pb[i] = (const char*)Bt + (size_t)(nBase + srow + i * 64) * K * 2 + (schunk << 4);
  }
  int ldst = tid * 16;

  auto STAGE = [&](int slot, size_t ko) {
    int b = slot * 16384;
#pragma unroll
    for (int i = 0; i < 2; ++i)
      __builtin_amdgcn_global_load_lds(GLBP(pa[i] + ko), LDSP(smem + b + i * 4096 + ldst), 16, 0, 0);
#pragma unroll
    for (int i = 0; i < 2; ++i)
      __builtin_amdgcn_global_load_lds(GLBP(pb[i] + ko), LDSP(smem + b + 8192 + i * 4096 + ldst), 16, 0, 0);
  };

  int offA[4], offB[4];
#pragma unroll
  for (int m = 0; m < 4; ++m) {
    int rr = wr * 64 + m * 16 + la;
    offA[m] = rr * 64 + ((lg ^ ((rr >> 1) & 3)) << 4);
  }
#pragma unroll
  for (int n = 0; n < 4; ++n) {
    int rr = wc * 64 + n * 16 + la;
    offB[n] = 8192 + rr * 64 + ((lg ^ ((rr >> 1) & 3)) << 4);
  }

  const f32x4 z4 = {0.f, 0.f, 0.f, 0.f};
  f32x4 acc[4][4];
#pragma unroll
  for (int m = 0; m < 4; ++m)
#pragma unroll
    for (int n = 0; n < 4; ++n) acc[m][n] = z4;

  int NT = K >> 5;
  STAGE(0, 0);
  STAGE(1, 64);
  int rs = 0;
  for (int t = 0; t < NT; ++t) {
    if (t + 1 < NT)
      asm volatile("s_waitcnt vmcnt(4)" ::: "memory");
    else
      asm volatile("s_waitcnt vmcnt(0)" ::: "memory");
    __builtin_amdgcn_s_barrier();
    __builtin_amdgcn_sched_barrier(0);
    if (t + 2 < NT) {
      int ws = rs + 2;
      if (ws >= 3) ws -= 3;
      STAGE(ws, (size_t)(t + 2) * 64);
    }
    const char* buf = (const char*)smem + rs * 16384;
    short8 af[4], bfr[4];
#pragma unroll
    for (int n = 0; n < 4; ++n) bfr[n] = *(const short8*)(buf + offB[n]);
#pragma unroll
    for (int m = 0; m < 4; ++m) af[m] = *(const short8*)(buf + offA[m]);
    __builtin_amdgcn_s_setprio(1);
#pragma unroll
    for (int m = 0; m < 4; ++m)
#pragma unroll
      for (int n = 0; n < 4; ++n)
        acc[m][n] = __builtin_amdgcn_mfma_f32_16x16x32_bf16(af[m], bfr[n], acc[m][n], 0, 0, 0);
    __builtin_amdgcn_s_setprio(0);
    rs = (rs == 2) ? 0 : rs + 1;
  }

#pragma unroll
  for (int m = 0; m < 4; ++m) {
#pragma unroll
    for (int n = 0; n < 4; ++n) {
      int col = nBase + wc * 64 + n * 16 + la;
      float bcol = bias[col];
#pragma unroll
      for (int j = 0; j < 4; ++j) {
        int row = mBase + wr * 64 + m * 16 + lg * 4 + j;
        if (row < ctok) {
          int b, py, px;
          tok2pix(w0 * 196 + row, b, py, px);
          bool pv = (py < 64 && px < 64);
          float v = acc[m][n][j] + bcol;
          if (EPI == 1) {
            float wv = pv ? ((const float*)res)[((size_t)((b * 64 + py) * 64 + px)) * 1280 + col]
                          : 0.f;
            ((unsigned short*)outp)[(size_t)row * 1280 + col] = f2bf(v + wv);
          } else {
            if (pv)
              ((float*)outp)[((size_t)((b * 64 + py) * 64 + px)) * 1280 + col] =
                  v + bf2f(((const unsigned short*)res)[(size_t)row * 1280 + col]);
          }
        }
      }
    }
  }
}

__global__ __launch_bounds__(256, 3) void k_gproj(const unsigned short* A, const unsigned short* Bt,
                                                  int K, int N, int gx, const float* bias, void* o,
                                                  const void* res, int w0, int ct) {
  gemm128_body<1>(A, Bt, K, N, gx, bias, o, res, w0, ct);
}
__global__ __launch_bounds__(256, 3) void k_gmlp2(const unsigned short* A, const unsigned short* Bt,
                                                  int K, int N, int gx, const float* bias, void* o,
                                                  const void* res, int w0, int ct) {
  gemm128_body<3>(A, Bt, K, N, gx, bias, o, res, w0, ct);
}

// ---------------- attention: bias fused into QK^T via one-hot K-extension ----------------
// K' = [K*scale (80) | onehot_ky (14) | onehot_kx (14) | 0 (20)]  (128 wide, XOR-swizzled rows)
// Q' = [Q (80) | BH(t,:) (14) | BW(t,:) (14) | 0]  ->  S' = scale*QK^T + bias  (one MFMA pass)
__global__ __launch_bounds__(512, 1) void k_attn(const unsigned short* __restrict__ qkv,
                                                 const float* __restrict__ rph,
                                                 const float* __restrict__ rpw,
                                                 unsigned short* __restrict__ AO) {
  __shared__ unsigned short Ks[208 * 128];  // 53.2KB, row-XOR swizzle byte^=(row&7)<<4
  __shared__ unsigned short Vt[80 * 232];   // [d][key] stride 116dw (2-way free)
  __shared__ unsigned short Ps[8][16 * 232];
  __shared__ unsigned short Bls[196 * 28];  // [t][BH(14) | BW(14)] bf16
  int wh = blockIdx.x;
  int w = wh >> 4, nh = wh & 15;
  int tid = threadIdx.x, wid = tid >> 6, lane = tid & 63;
  int la = lane & 15, lg = lane >> 4;
  const unsigned short* qb = qkv + (size_t)wh * 47040;
  const unsigned short* kb = qb + 15680;
  const unsigned short* vb = qb + 31360;
  const short8 z8 = {0, 0, 0, 0, 0, 0, 0, 0};
  const float scale = 0.111803398874989485f;  // 80^-0.5

  // K' staging: scaled K rows + one-hot bias selectors
  for (int c = tid; c < 208 * 16; c += 512) {
    int t = c >> 4, seg = c & 15;
    short8 kv = z8;
    if (t < 196) {
      if (seg < 10) {
        short8 raw = *(const short8*)(kb + (size_t)t * 80 + seg * 8);
#pragma unroll
        for (int e = 0; e < 8; ++e)
          kv[e] = (short)f2bf(bf2f((unsigned short)raw[e]) * scale);
      } else if (seg < 14) {
        int ky = t / 14, kx = t - ky * 14;
#pragma unroll
        for (int e = 0; e < 8; ++e) {
          int col = seg * 8 + e;
          kv[e] = (col == 80 + ky || col == 94 + kx) ? (short)0x3F80 : (short)0;
        }
      }
    }
    *(short8*)((char*)Ks + t * 256 + ((seg * 16) ^ ((t & 7) << 4))) = kv;
  }
  // V -> LDS transposed
  for (int c = tid; c < 1960; c += 512) {
    int t = c / 10, d8 = (c - t * 10) * 8;
    short8 vv = *(const short8*)(vb + (size_t)t * 80 + d8);
#pragma unroll
    for (int e = 0; e < 8; ++e) Vt[(d8 + e) * 232 + t] = (unsigned short)vv[e];
  }
  for (int i = tid; i < 80 * 36; i += 512) Vt[(i / 36) * 232 + 196 + (i % 36)] = 0;
  // decomposed rel-pos bias rows from contiguous head-major Q
  for (int id = tid; id < 196 * 28; id += 512) {
    int t = id / 28, c = id - t * 28;
    int y = t / 14, xx = t - y * 14;
    const float* R = (c < 14) ? (rph + (size_t)(y - c + 13) * 80)
                              : (rpw + (size_t)(xx - (c - 14) + 13) * 80);
    const unsigned short* qq = qb + (size_t)t * 80;
    float acc = 0.f;
#pragma unroll
    for (int d8 = 0; d8 < 10; ++d8) {
      short8 qv = *(const short8*)(qq + d8 * 8);
      const float4* Rv = (const float4*)(R + d8 * 8);
      float4 ra = Rv[0], rb = Rv[1];
      acc += bf2f((unsigned short)qv[0]) * ra.x + bf2f((unsigned short)qv[1]) * ra.y +
             bf2f((unsigned short)qv[2]) * ra.z + bf2f((unsigned short)qv[3]) * ra.w +
             bf2f((unsigned short)qv[4]) * rb.x + bf2f((unsigned short)qv[5]) * rb.y +
             bf2f((unsigned short)qv[6]) * rb.z + bf2f((unsigned short)qv[7]) * rb.w;
    }
    Bls[id] = f2bf(acc);
  }
  __syncthreads();

  const f32x4 z4 = {0.f, 0.f, 0.f, 0.f};
  unsigned short* P = Ps[wid];

  auto process = [&](int rb) {
    int t = rb * 16 + la;
    bool tv = t < 196;
    short8 qa[4];
#pragma unroll
    for (int kk = 0; kk < 2; ++kk)
      qa[kk] = tv ? *(const short8*)(qb + (size_t)t * 80 + kk * 32 + lg * 8) : z8;
    if (tv && lg < 2) {
      qa[2] = *(const short8*)(qb + (size_t)t * 80 + 64 + lg * 8);
    } else if (tv) {
      short8 rr = z8;
      int base = (lg - 2) * 8;
#pragma unroll
      for (int e = 0; e < 8; ++e) rr[e] = (short)Bls[t * 28 + base + e];
      qa[2] = rr;
    } else {
      qa[2] = z8;
    }
    {
      short8 rr = z8;
      if (tv && lg == 0) {
#pragma unroll
        for (int e = 0; e < 8; ++e) rr[e] = (short)Bls[t * 28 + 16 + e];
      } else if (tv && lg == 1) {
#pragma unroll
        for (int e = 0; e < 4; ++e) rr[e] = (short)Bls[t * 28 + 24 + e];
      }
      qa[3] = rr;
    }
    f32x4 s[13];
#pragma unroll
    for (int i = 0; i < 13; ++i) s[i] = z4;
#pragma unroll
    for (int kk = 0; kk < 4; ++kk) {
      int coff = (kk * 64 + lg * 16) ^ ((la & 7) << 4);
#pragma unroll
      for (int ni = 0; ni < 13; ++ni) {
        short8 bb = *(const short8*)((char*)Ks + (ni * 16 + la) * 256 + coff);
        s[ni] = __builtin_amdgcn_mfma_f32_16x16x32_bf16(qa[kk], bb, s[ni], 0, 0, 0);
      }
    }
#pragma unroll
    for (int j = 0; j < 4; ++j) {
      int rloc = lg * 4 + j;
      int tt = rb * 16 + rloc;
      bool ttv = tt < 196;
      float v[13];
      float mx = -3e30f;
#pragma unroll
      for (int ci = 0; ci < 13; ++ci) {
        int key = ci * 16 + la;
        float val = (key < 196 && ttv) ? s[ci][j] : -3e30f;
        v[ci] = val;
        mx = fmaxf(mx, val);
      }
#pragma unroll
      for (int o = 1; o < 16; o <<= 1) mx = fmaxf(mx, __shfl_xor(mx, o));
      float sum = 0.f;
#pragma unroll
      for (int ci = 0; ci < 13; ++ci) {
        float e = __expf(v[ci] - mx);
        v[ci] = e;
        sum += e;
      }
#pragma unroll
      for (int o = 1; o < 16; o <<= 1) sum += __shfl_xor(sum, o);
      float inv = 1.f / sum;
#pragma unroll
      for (int ci = 0; ci < 13; ++ci) P[rloc * 232 + ci * 16 + la] = f2bf(v[ci] * inv);
      P[rloc * 232 + 208 + la] = 0;
    }
    f32x4 o5[5];
#pragma unroll
    for (int i = 0; i < 5; ++i) o5[i] = z4;
#pragma unroll
    for (int kc = 0; kc < 7; ++kc) {
      short8 aa = *(const short8*)(P + la * 232 + kc * 32 + lg * 8);
#pragma unroll
      for (int ni = 0; ni < 5; ++ni) {
        short8 bb = *(const short8*)(Vt + (ni * 16 + la) * 232 + kc * 32 + lg * 8);
        o5[ni] = __builtin_amdgcn_mfma_f32_16x16x32_bf16(aa, bb, o5[ni], 0, 0, 0);
      }
    }
#pragma unroll
    for (int ni = 0; ni < 5; ++ni)
#pragma unroll
      for (int j = 0; j < 4; ++j) {
        int to = rb * 16 + lg * 4 + j;
        if (to < 196)
          AO[((size_t)w * 196 + to) * 1280 + nh * 80 + ni * 16 + la] = f2bf(o5[ni][j]);
      }
  };

  process(wid);                   // rb 0..7
  if (wid < 5) process(wid + 8);  // rb 8..12
}

extern "C" void kernel_launch(void* const* d_in, const int* in_sizes, int n_in,
                              void* d_out, int out_size, void* d_ws, size_t ws_size,
                              hipStream_t stream) {
  const float* x = (const float*)d_in[0];
  const float* ln1g = (const float*)d_in[1];
  const float* ln1b = (const float*)d_in[2];
  const float* qkvw = (const float*)d_in[3];
  const float* qkvb = (const float*)d_in[4];
  const float* projw = (const float*)d_in[5];
  const float* projb = (const float*)d_in[6];
  const float* rph = (const float*)d_in[7];
  const float* rpw = (const float*)d_in[8];
  const float* ln2g = (const float*)d_in[9];
  const float* ln2b = (const float*)d_in[10];
  const float* w1 = (const float*)d_in[11];
  const float* b1 = (const float*)d_in[12];
  const float* w2 = (const float*)d_in[13];
  const float* b2 = (const float*)d_in[14];
  float* out = (float*)d_out;

  const size_t woff = (3840ull * 1280 + 1280ull * 1280 + 5120ull * 1280 + 1280ull * 5120) * 2;
  // per-chunk ws/row: A1 2560 + QKV 7680 + AO 2560 + ATTN 2560 = 15360 (H overlays QKV+AO)
  const int NWopts[11] = {25, 20, 16, 14, 12, 10, 8, 5, 4, 2, 1};
  int NW = 0, Mb = 0;
  for (int i = 0; i < 11; ++i) {
    int nw = NWopts[i];
    int mb = ((nw * 196 + 255) / 256) * 256;
    size_t tot = woff + (size_t)mb * 15360;
    if (tot <= ws_size) { NW = nw; Mb = mb; break; }
  }
  if (!NW) return;

  char* p = (char*)d_ws;
  unsigned short* qkvwT = (unsigned short*)p; p += 3840ull * 1280 * 2;
  unsigned short* projwT = (unsigned short*)p; p += 1280ull * 1280 * 2;
  unsigned short* w1T = (unsigned short*)p; p += 5120ull * 1280 * 2;
  unsigned short* w2T = (unsigned short*)p; p += 1280ull * 5120 * 2;
  unsigned short* A1 = (unsigned short*)p; p += (size_t)Mb * 2560;
  unsigned short* QKV = (unsigned short*)p; p += (size_t)Mb * 7680;
  unsigned short* AO = (unsigned short*)p; p += (size_t)Mb * 2560;
  unsigned short* ATTN = (unsigned short*)p;
  unsigned short* Hb = QKV;  // MLP hidden (Mb x 5120) overlays QKV+AO (contiguous, both dead)
  unsigned short* A2 = A1;   // LN2 out overlays LN1 out

  k_transpose<<<dim3(120, 40), dim3(32, 8), 0, stream>>>(qkvw, qkvwT, 1280, 3840);
  k_transpose<<<dim3(40, 40), dim3(32, 8), 0, stream>>>(projw, projwT, 1280, 1280);
  k_transpose<<<dim3(160, 40), dim3(32, 8), 0, stream>>>(w1, w1T, 1280, 5120);
  k_transpose<<<dim3(40, 160), dim3(32, 8), 0, stream>>>(w2, w2T, 5120, 1280);

  int gy256 = Mb / 256, gy128 = Mb / 128;
  int nchunks = (100 + NW - 1) / NW;
  for (int c = 0; c < nchunks; ++c) {
    int w0 = c * NW;
    int cw = (100 - w0 < NW) ? (100 - w0) : NW;
    int ctok = cw * 196;
    k_ln1<<<Mb / 4, 256, 0, stream>>>(x, ln1g, ln1b, A1, w0, ctok);
    k_gqkv<<<30 * gy256, 512, 0, stream>>>(A1, qkvwT, 1280, 3840, 30, qkvb, (void*)QKV, ctok);
    k_attn<<<cw * 16, 512, 0, stream>>>(QKV, rph, rpw, AO);
    k_gproj<<<10 * gy128, 256, 0, stream>>>(AO, projwT, 1280, 1280, 10, projb, (void*)ATTN,
                                            (const void*)x, w0, ctok);
    k_ln2<<<Mb / 4, 256, 0, stream>>>(ATTN, ln2g, ln2b, A2);
    k_gmlp1<<<40 * gy256, 512, 0, stream>>>(A2, w1T, 1280, 5120, 40, b1, (void*)Hb, ctok);
    k_gmlp2<<<10 * gy128, 256, 0, stream>>>(Hb, w2T, 5120, 1280, 10, b2, (void*)out,
                                            (const void*)ATTN, w0, ctok);
  }
}

// Round 13
// 1802.822 us; speedup vs baseline: 1.2152x; 1.0081x over previous
//
#include <hip/hip_runtime.h>

typedef __attribute__((ext_vector_type(8))) short short8;
typedef __attribute__((ext_vector_type(4))) float f32x4;

#define GLBP(p) ((const __attribute__((address_space(1))) void*)(p))
#define LDSP(p) ((__attribute__((address_space(3))) void*)(p))

__device__ __forceinline__ float bf2f(unsigned short u) {
  return __uint_as_float(((unsigned int)u) << 16);
}
__device__ __forceinline__ unsigned short f2bf(float f) {
  unsigned int u = __float_as_uint(f);
  u += 0x7fff + ((u >> 16) & 1);
  return (unsigned short)(u >> 16);
}

// global token -> (batch, pixel-y, pixel-x); windows are 14x14, 5x5 grid/batch
__device__ __forceinline__ void tok2pix(int gt, int& b, int& py, int& px) {
  int w = gt / 196, t = gt - w * 196;
  b = w / 25;
  int wr = w - b * 25;
  int wy = wr / 5, wx = wr - wy * 5;
  int ty = t / 14;
  py = wy * 14 + ty;
  px = wx * 14 + (t - ty * 14);
}

// ---------------- weight transpose fp32(K,N) -> bf16(N,K) ----------------
__global__ void k_transpose(const float* __restrict__ W, unsigned short* __restrict__ Wt,
                            int K, int N) {
  __shared__ float tile[32][33];
  int tx = threadIdx.x, ty = threadIdx.y;
  int n0 = blockIdx.x * 32, k0 = blockIdx.y * 32;
#pragma unroll
  for (int i = 0; i < 4; ++i)
    tile[ty + 8 * i][tx] = W[(size_t)(k0 + ty + 8 * i) * N + n0 + tx];
  __syncthreads();
#pragma unroll
  for (int i = 0; i < 4; ++i)
    Wt[(size_t)(n0 + ty + 8 * i) * K + k0 + tx] = f2bf(tile[tx][ty + 8 * i]);
}

// ---------------- LN1: one wave per token row ----------------
__global__ __launch_bounds__(256) void k_ln1(const float* __restrict__ x,
                                             const float* __restrict__ g,
                                             const float* __restrict__ be,
                                             unsigned short* __restrict__ A1,
                                             int w0, int ctok) {
  int m = blockIdx.x * 4 + (threadIdx.x >> 6);
  int lane = threadIdx.x & 63;
  int b, py, px;
  tok2pix(w0 * 196 + m, b, py, px);
  bool valid = (m < ctok) && (py < 64) && (px < 64);
  const float* row = x + ((size_t)((b * 64 + py) * 64 + px)) * 1280;
  float v[20];
#pragma unroll
  for (int i = 0; i < 20; ++i) v[i] = valid ? row[lane + 64 * i] : 0.f;
  float s = 0.f, ss = 0.f;
#pragma unroll
  for (int i = 0; i < 20; ++i) { s += v[i]; ss += v[i] * v[i]; }
#pragma unroll
  for (int o = 32; o > 0; o >>= 1) { s += __shfl_down(s, o); ss += __shfl_down(ss, o); }
  s = __shfl(s, 0);
  ss = __shfl(ss, 0);
  float mu = s * (1.f / 1280.f);
  float var = ss * (1.f / 1280.f) - mu * mu;
  float rinv = rsqrtf(var + 1e-6f);
  unsigned short* o1 = A1 + (size_t)m * 1280;
#pragma unroll
  for (int i = 0; i < 20; ++i) {
    int c = lane + 64 * i;
    o1[c] = f2bf((v[i] - mu) * rinv * g[c] + be[c]);
  }
}

// ---------------- LN2: one wave per bf16 ATTN row ----------------
__global__ __launch_bounds__(256) void k_ln2(const unsigned short* __restrict__ AT,
                                             const float* __restrict__ g,
                                             const float* __restrict__ be,
                                             unsigned short* __restrict__ A2) {
  int m = blockIdx.x * 4 + (threadIdx.x >> 6);
  int lane = threadIdx.x & 63;
  const unsigned short* row = AT + (size_t)m * 1280;
  float v[20];
#pragma unroll
  for (int i = 0; i < 20; ++i) v[i] = bf2f(row[lane + 64 * i]);
  float s = 0.f, ss = 0.f;
#pragma unroll
  for (int i = 0; i < 20; ++i) { s += v[i]; ss += v[i] * v[i]; }
#pragma unroll
  for (int o = 32; o > 0; o >>= 1) { s += __shfl_down(s, o); ss += __shfl_down(ss, o); }
  s = __shfl(s, 0);
  ss = __shfl(ss, 0);
  float mu = s * (1.f / 1280.f);
  float var = ss * (1.f / 1280.f) - mu * mu;
  float rinv = rsqrtf(var + 1e-6f);
  unsigned short* o1 = A2 + (size_t)m * 1280;
#pragma unroll
  for (int i = 0; i < 20; ++i) {
    int c = lane + 64 * i;
    o1[c] = f2bf((v[i] - mu) * rinv * g[c] + be[c]);
  }
}

// ---------------- 256x128 bf16 GEMM, BK=32, 3-slot ring (72KB -> 2 blocks/CU) ----------------
// EPI 0: +bias -> head-major QKV bf16 [w][nh][q|k|v][196][80]
// EPI 1: +bias + window-residual(x) -> bf16 ATTN rows
// EPI 2: +bias + exact gelu -> bf16
// EPI 3: +bias + ATTN residual -> f32 d_out, window->image crop
template <int EPI>
__device__ __forceinline__ void gemm_body(const unsigned short* __restrict__ A,
                                          const unsigned short* __restrict__ Bt,
                                          int K, int N, int gx,
                                          const float* __restrict__ bias,
                                          void* __restrict__ outp,
                                          const float* __restrict__ xres,
                                          const unsigned short* __restrict__ attnres,
                                          int w0, int ctok) {
  __shared__ __align__(16) char smem[73728];  // 3 slots x (A 16KB + B 8KB)
  int tid = threadIdx.x;
  int w = tid >> 6, lane = tid & 63;
  // bijective XCD swizzle (m204)
  int nwg = gridDim.x, bid = blockIdx.x;
  int q = nwg >> 3, r = nwg & 7;
  int xcd = bid & 7, loc = bid >> 3;
  int wg = (xcd < r ? xcd * (q + 1) : r * (q + 1) + (xcd - r) * q) + loc;
  int bx = wg % gx, by = wg / gx;
  int mBase = by * 256, nBase = bx * 128;
  int wr = w >> 2, wc = w & 3;
  int la = lane & 15, lg = lane >> 4;

  int srow = tid >> 2;
  int schunk = (tid & 3) ^ ((srow >> 1) & 3);  // pre-swizzled source chunk
  const char* pa0 = (const char*)A + (size_t)(mBase + srow) * K * 2 + (schunk << 4);
  const char* pa1 = (const char*)A + (size_t)(mBase + 128 + srow) * K * 2 + (schunk << 4);
  const char* pb0 = (const char*)Bt + (size_t)(nBase + srow) * K * 2 + (schunk << 4);
  int ldst = tid * 16;

  auto STAGE = [&](int slot, size_t ko) {
    int b = slot * 24576;
    __builtin_amdgcn_global_load_lds(GLBP(pa0 + ko), LDSP(smem + b + ldst), 16, 0, 0);
    __builtin_amdgcn_global_load_lds(GLBP(pa1 + ko), LDSP(smem + b + 8192 + ldst), 16, 0, 0);
    __builtin_amdgcn_global_load_lds(GLBP(pb0 + ko), LDSP(smem + b + 16384 + ldst), 16, 0, 0);
  };

  int offA[8], offB[2];
#pragma unroll
  for (int m = 0; m < 8; ++m) {
    int rr = wr * 128 + m * 16 + la;
    offA[m] = rr * 64 + ((lg ^ ((rr >> 1) & 3)) << 4);
  }
#pragma unroll
  for (int n = 0; n < 2; ++n) {
    int rr = wc * 32 + n * 16 + la;
    offB[n] = 16384 + rr * 64 + ((lg ^ ((rr >> 1) & 3)) << 4);
  }

  const f32x4 z4 = {0.f, 0.f, 0.f, 0.f};
  f32x4 acc[8][2];
#pragma unroll
  for (int m = 0; m < 8; ++m)
#pragma unroll
    for (int n = 0; n < 2; ++n) acc[m][n] = z4;

  int NT = K >> 5;
  STAGE(0, 0);
  STAGE(1, 64);
  int rs = 0;
  for (int t = 0; t < NT; ++t) {
    if (t + 1 < NT)
      asm volatile("s_waitcnt vmcnt(3)" ::: "memory");
    else
      asm volatile("s_waitcnt vmcnt(0)" ::: "memory");
    __builtin_amdgcn_s_barrier();
    __builtin_amdgcn_sched_barrier(0);
    if (t + 2 < NT) {
      int ws = rs + 2;
      if (ws >= 3) ws -= 3;
      STAGE(ws, (size_t)(t + 2) * 64);
    }
    const char* buf = (const char*)smem + rs * 24576;
    short8 af[4], bfr[2];
#pragma unroll
    for (int n = 0; n < 2; ++n) bfr[n] = *(const short8*)(buf + offB[n]);
#pragma unroll
    for (int m = 0; m < 4; ++m) af[m] = *(const short8*)(buf + offA[m]);
    __builtin_amdgcn_s_setprio(1);
#pragma unroll
    for (int m = 0; m < 4; ++m)
#pragma unroll
      for (int n = 0; n < 2; ++n)
        acc[m][n] = __builtin_amdgcn_mfma_f32_16x16x32_bf16(af[m], bfr[n], acc[m][n], 0, 0, 0);
    __builtin_amdgcn_s_setprio(0);
    __builtin_amdgcn_sched_barrier(0);
#pragma unroll
    for (int m = 0; m < 4; ++m) af[m] = *(const short8*)(buf + offA[m + 4]);
    __builtin_amdgcn_s_setprio(1);
#pragma unroll
    for (int m = 0; m < 4; ++m)
#pragma unroll
      for (int n = 0; n < 2; ++n)
        acc[m + 4][n] = __builtin_amdgcn_mfma_f32_16x16x32_bf16(af[m], bfr[n], acc[m + 4][n], 0, 0, 0);
    __builtin_amdgcn_s_setprio(0);
    rs = (rs == 2) ? 0 : rs + 1;
  }

#pragma unroll
  for (int m = 0; m < 8; ++m) {
#pragma unroll
    for (int n = 0; n < 2; ++n) {
      int col = nBase + wc * 32 + n * 16 + la;
      float bcol = bias[col];
#pragma unroll
      for (int j = 0; j < 4; ++j) {
        int row = mBase + wr * 128 + m * 16 + lg * 4 + j;
        float v = acc[m][n][j] + bcol;
        if (EPI == 0) {
          if (row < ctok) {
            int wloc = row / 196, tt = row - wloc * 196;
            int which = col / 1280, cr = col - which * 1280;
            int nh = cr / 80, d = cr - nh * 80;
            ((unsigned short*)outp)[((((size_t)wloc * 16 + nh) * 3 + which) * 196 + tt) * 80 + d] =
                f2bf(v);
          }
        } else if (EPI == 2) {
          float gg = 0.5f * v * (1.f + erff(v * 0.70710678118654752f));
          ((unsigned short*)outp)[(size_t)row * N + col] = f2bf(gg);
        } else if (EPI == 1) {
          if (row < ctok) {
            int b, py, px;
            tok2pix(w0 * 196 + row, b, py, px);
            float wv = (py < 64 && px < 64)
                           ? xres[((size_t)((b * 64 + py) * 64 + px)) * 1280 + col]
                           : 0.f;
            ((unsigned short*)outp)[(size_t)row * 1280 + col] = f2bf(v + wv);
          }
        } else {
          if (row < ctok) {
            int b, py, px;
            tok2pix(w0 * 196 + row, b, py, px);
            if (py < 64 && px < 64)
              ((float*)outp)[((size_t)((b * 64 + py) * 64 + px)) * 1280 + col] =
                  v + bf2f(attnres[(size_t)row * 1280 + col]);
          }
        }
      }
    }
  }
}

__global__ __launch_bounds__(512, 4) void k_gqkv(const unsigned short* A, const unsigned short* Bt,
                                                 int K, int N, int gx, const float* bias, void* o,
                                                 const float* xr, const unsigned short* ar, int w0, int ct) {
  gemm_body<0>(A, Bt, K, N, gx, bias, o, xr, ar, w0, ct);
}
__global__ __launch_bounds__(512, 4) void k_gproj(const unsigned short* A, const unsigned short* Bt,
                                                  int K, int N, int gx, const float* bias, void* o,
                                                  const float* xr, const unsigned short* ar, int w0, int ct) {
  gemm_body<1>(A, Bt, K, N, gx, bias, o, xr, ar, w0, ct);
}
__global__ __launch_bounds__(512, 4) void k_gmlp1(const unsigned short* A, const unsigned short* Bt,
                                                  int K, int N, int gx, const float* bias, void* o,
                                                  const float* xr, const unsigned short* ar, int w0, int ct) {
  gemm_body<2>(A, Bt, K, N, gx, bias, o, xr, ar, w0, ct);
}
__global__ __launch_bounds__(512, 4) void k_gmlp2(const unsigned short* A, const unsigned short* Bt,
                                                  int K, int N, int gx, const float* bias, void* o,
                                                  const float* xr, const unsigned short* ar, int w0, int ct) {
  gemm_body<3>(A, Bt, K, N, gx, bias, o, xr, ar, w0, ct);
}

// ---------------- attention: bias fused into QK^T via one-hot K-extension (R12, proven) ----------------
// K' = [K*scale (80) | onehot_ky (14) | onehot_kx (14) | 0 (20)]  (128 wide, XOR-swizzled rows)
// Q' = [Q (80) | BH(t,:) (14) | BW(t,:) (14) | 0]  ->  S' = scale*QK^T + bias  (one MFMA pass)
__global__ __launch_bounds__(512, 1) void k_attn(const unsigned short* __restrict__ qkv,
                                                 const float* __restrict__ rph,
                                                 const float* __restrict__ rpw,
                                                 unsigned short* __restrict__ AO) {
  __shared__ unsigned short Ks[208 * 128];  // row-XOR swizzle byte^=(row&7)<<4
  __shared__ unsigned short Vt[80 * 232];   // [d][key] stride 116dw (2-way free)
  __shared__ unsigned short Ps[8][16 * 232];
  __shared__ unsigned short Bls[196 * 28];  // [t][BH(14) | BW(14)] bf16
  int wh = blockIdx.x;
  int w = wh >> 4, nh = wh & 15;
  int tid = threadIdx.x, wid = tid >> 6, lane = tid & 63;
  int la = lane & 15, lg = lane >> 4;
  const unsigned short* qb = qkv + (size_t)wh * 47040;
  const unsigned short* kb = qb + 15680;
  const unsigned short* vb = qb + 31360;
  const short8 z8 = {0, 0, 0, 0, 0, 0, 0, 0};
  const float scale = 0.111803398874989485f;  // 80^-0.5

  // K' staging: scaled K rows + one-hot bias selectors
  for (int c = tid; c < 208 * 16; c += 512) {
    int t = c >> 4, seg = c & 15;
    short8 kv = z8;
    if (t < 196) {
      if (seg < 10) {
        short8 raw = *(const short8*)(kb + (size_t)t * 80 + seg * 8);
#pragma unroll
        for (int e = 0; e < 8; ++e)
          kv[e] = (short)f2bf(bf2f((unsigned short)raw[e]) * scale);
      } else if (seg < 14) {
        int ky = t / 14, kx = t - ky * 14;
#pragma unroll
        for (int e = 0; e < 8; ++e) {
          int col = seg * 8 + e;
          kv[e] = (col == 80 + ky || col == 94 + kx) ? (short)0x3F80 : (short)0;
        }
      }
    }
    *(short8*)((char*)Ks + t * 256 + ((seg * 16) ^ ((t & 7) << 4))) = kv;
  }
  // V -> LDS transposed
  for (int c = tid; c < 1960; c += 512) {
    int t = c / 10, d8 = (c - t * 10) * 8;
    short8 vv = *(const short8*)(vb + (size_t)t * 80 + d8);
#pragma unroll
    for (int e = 0; e < 8; ++e) Vt[(d8 + e) * 232 + t] = (unsigned short)vv[e];
  }
  for (int i = tid; i < 80 * 36; i += 512) Vt[(i / 36) * 232 + 196 + (i % 36)] = 0;
  // decomposed rel-pos bias rows from contiguous head-major Q
  for (int id = tid; id < 196 * 28; id += 512) {
    int t = id / 28, c = id - t * 28;
    int y = t / 14, xx = t - y * 14;
    const float* R = (c < 14) ? (rph + (size_t)(y - c + 13) * 80)
                              : (rpw + (size_t)(xx - (c - 14) + 13) * 80);
    const unsigned short* qq = qb + (size_t)t * 80;
    float acc = 0.f;
#pragma unroll
    for (int d8 = 0; d8 < 10; ++d8) {
      short8 qv = *(const short8*)(qq + d8 * 8);
      const float4* Rv = (const float4*)(R + d8 * 8);
      float4 ra = Rv[0], rb = Rv[1];
      acc += bf2f((unsigned short)qv[0]) * ra.x + bf2f((unsigned short)qv[1]) * ra.y +
             bf2f((unsigned short)qv[2]) * ra.z + bf2f((unsigned short)qv[3]) * ra.w +
             bf2f((unsigned short)qv[4]) * rb.x + bf2f((unsigned short)qv[5]) * rb.y +
             bf2f((unsigned short)qv[6]) * rb.z + bf2f((unsigned short)qv[7]) * rb.w;
    }
    Bls[id] = f2bf(acc);
  }
  __syncthreads();

  const f32x4 z4 = {0.f, 0.f, 0.f, 0.f};
  unsigned short* P = Ps[wid];

  auto process = [&](int rb) {
    int t = rb * 16 + la;
    bool tv = t < 196;
    short8 qa[4];
#pragma unroll
    for (int kk = 0; kk < 2; ++kk)
      qa[kk] = tv ? *(const short8*)(qb + (size_t)t * 80 + kk * 32 + lg * 8) : z8;
    if (tv && lg < 2) {
      qa[2] = *(const short8*)(qb + (size_t)t * 80 + 64 + lg * 8);
    } else if (tv) {
      short8 rr = z8;
      int base = (lg - 2) * 8;
#pragma unroll
      for (int e = 0; e < 8; ++e) rr[e] = (short)Bls[t * 28 + base + e];
      qa[2] = rr;
    } else {
      qa[2] = z8;
    }
    {
      short8 rr = z8;
      if (tv && lg == 0) {
#pragma unroll
        for (int e = 0; e < 8; ++e) rr[e] = (short)Bls[t * 28 + 16 + e];
      } else if (tv && lg == 1) {
#pragma unroll
        for (int e = 0; e < 4; ++e) rr[e] = (short)Bls[t * 28 + 24 + e];
      }
      qa[3] = rr;
    }
    f32x4 s[13];
#pragma unroll
    for (int i = 0; i < 13; ++i) s[i] = z4;
#pragma unroll
    for (int kk = 0; kk < 4; ++kk) {
      int coff = (kk * 64 + lg * 16) ^ ((la & 7) << 4);
#pragma unroll
      for (int ni = 0; ni < 13; ++ni) {
        short8 bb = *(const short8*)((char*)Ks + (ni * 16 + la) * 256 + coff);
        s[ni] = __builtin_amdgcn_mfma_f32_16x16x32_bf16(qa[kk], bb, s[ni], 0, 0, 0);
      }
    }
#pragma unroll
    for (int j = 0; j < 4; ++j) {
      int rloc = lg * 4 + j;
      int tt = rb * 16 + rloc;
      bool ttv = tt < 196;
      float v[13];
      float mx = -3e30f;
#pragma unroll
      for (int ci = 0; ci < 13; ++ci) {
        int key = ci * 16 + la;
        float val = (key < 196 && ttv) ? s[ci][j] : -3e30f;
        v[ci] = val;
        mx = fmaxf(mx, val);
      }
#pragma unroll
      for (int o = 1; o < 16; o <<= 1) mx = fmaxf(mx, __shfl_xor(mx, o));
      float sum = 0.f;
#pragma unroll
      for (int ci = 0; ci < 13; ++ci) {
        float e = __expf(v[ci] - mx);
        v[ci] = e;
        sum += e;
      }
#pragma unroll
      for (int o = 1; o < 16; o <<= 1) sum += __shfl_xor(sum, o);
      float inv = 1.f / sum;
#pragma unroll
      for (int ci = 0; ci < 13; ++ci) P[rloc * 232 + ci * 16 + la] = f2bf(v[ci] * inv);
      P[rloc * 232 + 208 + la] = 0;
    }
    f32x4 o5[5];
#pragma unroll
    for (int i = 0; i < 5; ++i) o5[i] = z4;
#pragma unroll
    for (int kc = 0; kc < 7; ++kc) {
      short8 aa = *(const short8*)(P + la * 232 + kc * 32 + lg * 8);
#pragma unroll
      for (int ni = 0; ni < 5; ++ni) {
        short8 bb = *(const short8*)(Vt + (ni * 16 + la) * 232 + kc * 32 + lg * 8);
        o5[ni] = __builtin_amdgcn_mfma_f32_16x16x32_bf16(aa, bb, o5[ni], 0, 0, 0);
      }
    }
#pragma unroll
    for (int ni = 0; ni < 5; ++ni)
#pragma unroll
      for (int j = 0; j < 4; ++j) {
        int to = rb * 16 + lg * 4 + j;
        if (to < 196)
          AO[((size_t)w * 196 + to) * 1280 + nh * 80 + ni * 16 + la] = f2bf(o5[ni][j]);
      }
  };

  process(wid);                   // rb 0..7
  if (wid < 5) process(wid + 8);  // rb 8..12
}

extern "C" void kernel_launch(void* const* d_in, const int* in_sizes, int n_in,
                              void* d_out, int out_size, void* d_ws, size_t ws_size,
                              hipStream_t stream) {
  const float* x = (const float*)d_in[0];
  const float* ln1g = (const float*)d_in[1];
  const float* ln1b = (const float*)d_in[2];
  const float* qkvw = (const float*)d_in[3];
  const float* qkvb = (const float*)d_in[4];
  const float* projw = (const float*)d_in[5];
  const float* projb = (const float*)d_in[6];
  const float* rph = (const float*)d_in[7];
  const float* rpw = (const float*)d_in[8];
  const float* ln2g = (const float*)d_in[9];
  const float* ln2b = (const float*)d_in[10];
  const float* w1 = (const float*)d_in[11];
  const float* b1 = (const float*)d_in[12];
  const float* w2 = (const float*)d_in[13];
  const float* b2 = (const float*)d_in[14];
  float* out = (float*)d_out;

  const size_t woff = (3840ull * 1280 + 1280ull * 1280 + 5120ull * 1280 + 1280ull * 5120) * 2;
  // per-chunk ws/row: A1 2560 + QKV 7680 + AO 2560 + ATTN 2560 = 15360 (H overlays QKV+AO)
  const int NWopts[10] = {25, 20, 16, 12, 10, 8, 5, 4, 2, 1};
  int NW = 0, Mb = 0;
  for (int i = 0; i < 10; ++i) {
    int nw = NWopts[i];
    int mb = ((nw * 196 + 255) / 256) * 256;
    size_t tot = woff + (size_t)mb * 15360;
    if (tot <= ws_size) { NW = nw; Mb = mb; break; }
  }
  if (!NW) return;

  char* p = (char*)d_ws;
  unsigned short* qkvwT = (unsigned short*)p; p += 3840ull * 1280 * 2;
  unsigned short* projwT = (unsigned short*)p; p += 1280ull * 1280 * 2;
  unsigned short* w1T = (unsigned short*)p; p += 5120ull * 1280 * 2;
  unsigned short* w2T = (unsigned short*)p; p += 1280ull * 5120 * 2;
  unsigned short* A1 = (unsigned short*)p; p += (size_t)Mb * 2560;
  unsigned short* QKV = (unsigned short*)p; p += (size_t)Mb * 7680;
  unsigned short* AO = (unsigned short*)p; p += (size_t)Mb * 2560;
  unsigned short* ATTN = (unsigned short*)p;
  unsigned short* Hb = QKV;  // MLP hidden (Mb x 5120) overlays QKV+AO (contiguous, both dead)
  unsigned short* A2 = A1;   // LN2 out overlays LN1 out

  k_transpose<<<dim3(120, 40), dim3(32, 8), 0, stream>>>(qkvw, qkvwT, 1280, 3840);
  k_transpose<<<dim3(40, 40), dim3(32, 8), 0, stream>>>(projw, projwT, 1280, 1280);
  k_transpose<<<dim3(160, 40), dim3(32, 8), 0, stream>>>(w1, w1T, 1280, 5120);
  k_transpose<<<dim3(40, 160), dim3(32, 8), 0, stream>>>(w2, w2T, 5120, 1280);

  int gy = Mb / 256;
  int nchunks = (100 + NW - 1) / NW;
  for (int c = 0; c < nchunks; ++c) {
    int w0 = c * NW;
    int cw = (100 - w0 < NW) ? (100 - w0) : NW;
    int ctok = cw * 196;
    k_ln1<<<Mb / 4, 256, 0, stream>>>(x, ln1g, ln1b, A1, w0, ctok);
    k_gqkv<<<30 * gy, 512, 0, stream>>>(A1, qkvwT, 1280, 3840, 30, qkvb, (void*)QKV,
                                        nullptr, nullptr, 0, ctok);
    k_attn<<<cw * 16, 512, 0, stream>>>(QKV, rph, rpw, AO);
    k_gproj<<<10 * gy, 512, 0, stream>>>(AO, projwT, 1280, 1280, 10, projb, (void*)ATTN,
                                         x, nullptr, w0, ctok);
    k_ln2<<<Mb / 4, 256, 0, stream>>>(ATTN, ln2g, ln2b, A2);
    k_gmlp1<<<40 * gy, 512, 0, stream>>>(A2, w1T, 1280, 5120, 40, b1, (void*)Hb,
                                         nullptr, nullptr, 0, ctok);
    k_gmlp2<<<10 * gy, 512, 0, stream>>>(Hb, w2T, 5120, 1280, 10, b2, (void*)out,
                                         nullptr, ATTN, w0, ctok);
  }
}